// Round 1
// baseline (78.300 us; speedup 1.0000x reference)
//
#include <hip/hip_runtime.h>

// Problem constants (B, I, C, U, S) = (256, 8, 1152, 10, 16)
#define B_DIM 256
#define I_DIM 8
#define C_DIM 1152
#define U_DIM 10
#define S_DIM 16
#define ROW (I_DIM * C_DIM)   // 9216 floats per batch element

// Single fused kernel: 72 blocks x 256 threads, 16 capsules (c) per block.
// Phase 1: batch-reduce x[:, :, c0:c0+16] -> xs[16][8].
//   Thread map tid = b8*32 + i*4 + cq: each thread sums 32 consecutive b's of a
//   float4 (4 consecutive c). Per wave-instruction: 16 segments x 64B -> fully
//   coalesced. Disjoint c-columns per block -> x is read exactly once (9.4 MB).
// Phase 2: routing, register resident. thread = (c_local = tid>>4, s = tid&15).
//   W fragments (20 float4 / thread, 5.9 MB total, read once, coalesced) are
//   prefetched into VGPRs BEFORE phase 1 so HBM latency hides under the x loop.
// No workspace, one dispatch: removes one launch gap + 0.6 MB partial
// round-trip vs the 2-kernel version.
__global__ __launch_bounds__(256) void capsule_fused(
    const float* __restrict__ x, const float* __restrict__ W,
    float* __restrict__ out) {
  __shared__ float4 fold[256];
  __shared__ float xs_lds[16][I_DIM];

  const int tid = threadIdx.x;
  const int c0 = blockIdx.x * 16;
  const int c_local = tid >> 4;          // 0..15
  const int s = tid & 15;                // 0..15
  const int c = c0 + c_local;

  // ---- W prefetch (no dependencies; issues before the x loads) ----
  // W float layout: ((c*U + u)*S + s)*I ; for fixed (c,s), u-stride = 128 floats.
  const float4* wp =
      (const float4*)(W + (size_t)c * (U_DIM * S_DIM * I_DIM) + s * I_DIM);
  float4 wreg[U_DIM][2];
#pragma unroll
  for (int u = 0; u < U_DIM; ++u) {
    wreg[u][0] = wp[u * (S_DIM * I_DIM / 4)];
    wreg[u][1] = wp[u * (S_DIM * I_DIM / 4) + 1];
  }

  // ---- Phase 1: xs[c_l][i] = sum_b x[b, i, c0 + c_l] ----
  {
    const int b8 = tid >> 5;             // 0..7 (32 b each)
    const int i = (tid >> 2) & 7;        // 0..7
    const int cq = tid & 3;              // c quad: c = c0 + cq*4 .. +3
    const float* p = x + (size_t)(b8 * 32) * ROW + i * C_DIM + c0 + cq * 4;
    float4 acc = {0.f, 0.f, 0.f, 0.f};
    // unroll 16: caps in-flight loads so wreg (80 VGPR) + pipeline fits w/o spill
#pragma unroll 16
    for (int j = 0; j < 32; ++j) {
      const float4 v = *(const float4*)(p + (size_t)j * ROW);
      acc.x += v.x; acc.y += v.y; acc.z += v.z; acc.w += v.w;
    }
    fold[tid] = acc;
  }
  __syncthreads();
  if (tid < 32) {                        // tid = i*4 + cq
    float4 a = fold[tid];
#pragma unroll
    for (int k = 1; k < 8; ++k) {
      const float4 v = fold[k * 32 + tid];
      a.x += v.x; a.y += v.y; a.z += v.z; a.w += v.w;
    }
    const int i = tid >> 2, cq = tid & 3;
    xs_lds[cq * 4 + 0][i] = a.x;
    xs_lds[cq * 4 + 1][i] = a.y;
    xs_lds[cq * 4 + 2][i] = a.z;
    xs_lds[cq * 4 + 3][i] = a.w;
  }
  __syncthreads();

  // ---- Phase 2: routing (identical math to the verified 2-kernel version) ----
  float xs[I_DIM];
#pragma unroll
  for (int i = 0; i < I_DIM; ++i) xs[i] = xs_lds[c_local][i];

  float us[U_DIM];
#pragma unroll
  for (int u = 0; u < U_DIM; ++u) {
    const float4 w0 = wreg[u][0], w1 = wreg[u][1];
    us[u] = w0.x * xs[0] + w0.y * xs[1] + w0.z * xs[2] + w0.w * xs[3] +
            w1.x * xs[4] + w1.y * xs[5] + w1.z * xs[6] + w1.w * xs[7];
  }

  float bij[U_DIM];
  float v[U_DIM];

  // iteration 0: softmax(0) == 1/10 exactly
#pragma unroll
  for (int u = 0; u < U_DIM; ++u) {
    const float sj = 0.1f * us[u];
    float msq = sj * sj;
#pragma unroll
    for (int w = 1; w < 16; w <<= 1) msq += __shfl_xor(msq, w);
    const float mag = sqrtf(msq);
    const float v0 = (msq / (1.f + msq)) * (sj / mag);
    v[u] = v0;
    float a = us[u] * v0;
#pragma unroll
    for (int w = 1; w < 16; w <<= 1) a += __shfl_xor(a, w);
    bij[u] = a * (1.f / (float)B_DIM);
  }

  // iterations 1..2: full softmax; last iteration skips the agreement update
#pragma unroll
  for (int it = 1; it < 3; ++it) {
    float m = bij[0];
#pragma unroll
    for (int u = 1; u < U_DIM; ++u) m = fmaxf(m, bij[u]);
    float e[U_DIM];
    float sum = 0.f;
#pragma unroll
    for (int u = 0; u < U_DIM; ++u) { e[u] = __expf(bij[u] - m); sum += e[u]; }
    const float inv = 1.f / sum;

#pragma unroll
    for (int u = 0; u < U_DIM; ++u) {
      const float sj = e[u] * inv * us[u];
      float msq = sj * sj;
#pragma unroll
      for (int w = 1; w < 16; w <<= 1) msq += __shfl_xor(msq, w);
      const float mag = sqrtf(msq);
      const float vv = (msq / (1.f + msq)) * (sj / mag);
      v[u] = vv;
      if (it < 2) {
        float a = us[u] * vv;
#pragma unroll
        for (int w = 1; w < 16; w <<= 1) a += __shfl_xor(a, w);
        bij[u] += a * (1.f / (float)B_DIM);
      }
    }
  }

#pragma unroll
  for (int u = 0; u < U_DIM; ++u)
    out[(size_t)c * (U_DIM * S_DIM) + u * S_DIM + s] = v[u];
}

extern "C" void kernel_launch(void* const* d_in, const int* in_sizes, int n_in,
                              void* d_out, int out_size, void* d_ws, size_t ws_size,
                              hipStream_t stream) {
  const float* x = (const float*)d_in[0];  // [256, 8, 1152]
  const float* W = (const float*)d_in[1];  // [1, 1152, 10, 16, 8]
  float* out = (float*)d_out;              // [1152, 10, 16]
  (void)d_ws; (void)ws_size;               // workspace no longer used

  capsule_fused<<<dim3(C_DIM / 16), 256, 0, stream>>>(x, W, out);
}